// Round 5
// baseline (113.955 us; speedup 1.0000x reference)
//
#include <hip/hip_runtime.h>
#include <stdint.h>

#define BN_TOTAL 25600   // B*N = 256*100
#define DDIM 128
#define KN 16

typedef __bf16 bf16x8 __attribute__((ext_vector_type(8)));
typedef float f32x4 __attribute__((ext_vector_type(4)));
typedef float f32x16 __attribute__((ext_vector_type(16)));

__device__ __forceinline__ void gload_lds16(const void* g, void* l) {
    __builtin_amdgcn_global_load_lds(
        (const __attribute__((address_space(1))) void*)g,
        (__attribute__((address_space(3))) void*)l, 16, 0, 0);
}

// ---------------- Kernel 0: pre-build w1/w3 bf16 MFMA fragment images --------
// fw1: 32 slots (t*4+s) x 64 lanes of bf16x8 = 32 KB
// fw3: 64 slots (t*8+s) x 64 lanes of bf16x8 = 64 KB
__global__ __launch_bounds__(256) void k0_build_frags(
    const float* __restrict__ w1,   // [129,128]
    const float* __restrict__ w3,   // [256,128]
    bf16x8* __restrict__ fw1,
    bf16x8* __restrict__ fw3)
{
    const int slot = blockIdx.x * 256 + threadIdx.x;   // [0, 6144)
    if (slot < 2048) {
        const int idx  = slot >> 6;        // t*4+s
        const int lane = slot & 63;
        const int t = idx >> 2, s = idx & 3;
        const int grp = lane >> 4, lr = lane & 15;
        const int fbase = grp * 8 + 32 * s;
        const int d = t * 16 + lr;
        bf16x8 tmp;
        #pragma unroll
        for (int j = 0; j < 8; ++j)
            tmp[j] = (__bf16)w1[(fbase + j) * DDIM + d];
        fw1[slot] = tmp;
    } else {
        const int q = slot - 2048;         // [0, 4096)
        const int idx  = q >> 6;           // t*8+s
        const int lane = q & 63;
        const int t = idx >> 3, s = idx & 7;
        const int grp = lane >> 4, lr = lane & 15;
        const int fbase = grp * 8 + 32 * s;
        const int d = t * 16 + lr;
        bf16x8 tmp;
        #pragma unroll
        for (int j = 0; j < 8; ++j)
            tmp[j] = (__bf16)w3[(fbase + j) * DDIM + d];
        fw3[q] = tmp;
    }
}

// ---------------- Kernel 1: attention + aggregation -> agg bf16 [BN][128] ----
// Persistent: 1280 blocks x 4 waves, each wave handles 5 consecutive bn with
// NO barrier inside the loop. LDS staged once per block.
#define K1_ITERS 5
__global__ __launch_bounds__(256) void k1_attn_agg(
    const float* __restrict__ nbr,    // [BN,16,128]
    const float* __restrict__ wgt,    // [BN,16]
    const float* __restrict__ extra,  // [BN,128]
    const float* __restrict__ w1,     // [129,128]
    const float* __restrict__ w2,     // [128]
    const bf16x8* __restrict__ fw1,   // prebuilt fragments
    unsigned short* __restrict__ aggb)// [BN,128] bf16
{
    __shared__ bf16x8 b1frag[32][64];   // 32 KB
    __shared__ float w1last[DDIM];
    __shared__ float w2s[DDIM];

    const int tid  = threadIdx.x;
    const int lane = tid & 63;
    const int wave = tid >> 6;
    const int grp  = lane >> 4;   // 0..3
    const int lr   = lane & 15;   // 0..15
    const int half = lane >> 5;   // 0..1  (32x32 MFMA)
    const int col  = lane & 31;   // 0..31 (32x32 MFMA)

    // stage prebuilt w1 fragments: wave w loads slots w*8 .. w*8+7 (once/block)
    #pragma unroll
    for (int c = 0; c < 8; ++c)
        gload_lds16(fw1 + (wave * 8 + c) * 64 + lane, &b1frag[wave * 8 + c][0]);
    if (tid < DDIM) {
        w1last[tid] = w1[DDIM * DDIM + tid];
        w2s[tid]    = w2[tid];
    }
    __syncthreads();

    // hoist per-lane weight columns into registers (kills 16 ds_read per iter)
    float wl[8], w2v[8];
    #pragma unroll
    for (int t = 0; t < 8; ++t) {
        wl[t]  = w1last[t * 16 + lr];
        w2v[t] = w2s[t * 16 + lr];
    }

    const int base = (blockIdx.x * 4 + wave) * K1_ITERS;

    for (int it = 0; it < K1_ITERS; ++it) {
        const int bn = base + it;
        const float* nb = nbr   + (size_t)bn * (KN * DDIM);
        const float* ex = extra + (size_t)bn * DDIM;

        // acc init = weight[r] * w1[128][d]  (rows r = grp*4+j, col d = t*16+lr)
        const float4 wv = *(const float4*)(wgt + (size_t)bn * KN + grp * 4);
        f32x4 acc[8];
        #pragma unroll
        for (int t = 0; t < 8; ++t) {
            acc[t][0] = wv.x * wl[t];
            acc[t][1] = wv.y * wl[t];
            acc[t][2] = wv.z * wl[t];
            acc[t][3] = wv.w * wl[t];
        }

        // ---- stage 1: h = feat @ w1 (A-frags from global, B-frags from LDS)
        #pragma unroll
        for (int s = 0; s < 4; ++s) {
            const int f0 = grp * 8 + 32 * s;
            const float4 n0 = *(const float4*)(nb + lr * DDIM + f0);
            const float4 n1 = *(const float4*)(nb + lr * DDIM + f0 + 4);
            const float4 e0 = *(const float4*)(ex + f0);
            const float4 e1 = *(const float4*)(ex + f0 + 4);
            bf16x8 af;
            af[0] = (__bf16)(n0.x * e0.x); af[1] = (__bf16)(n0.y * e0.y);
            af[2] = (__bf16)(n0.z * e0.z); af[3] = (__bf16)(n0.w * e0.w);
            af[4] = (__bf16)(n1.x * e1.x); af[5] = (__bf16)(n1.y * e1.y);
            af[6] = (__bf16)(n1.z * e1.z); af[7] = (__bf16)(n1.w * e1.w);
            #pragma unroll
            for (int t = 0; t < 8; ++t)
                acc[t] = __builtin_amdgcn_mfma_f32_16x16x32_bf16(
                             af, b1frag[t * 4 + s][lane], acc[t], 0, 0, 0);
        }

        // ---- issue stage-2 B loads now (tile L1-hot); needed only after
        // softmax, so their latency hides under the shuffle/exp chain.
        // lane needs nbr[k = half*8+j][f = t*32+col]
        bf16x8 b2f[4];
        #pragma unroll
        for (int t = 0; t < 4; ++t)
            #pragma unroll
            for (int j = 0; j < 8; ++j)
                b2f[t][j] = (__bf16)nb[(half * 8 + j) * DDIM + t * 32 + col];

        // ---- leaky_relu(0.2) + dot with w2 -> logits for rows grp*4+r
        float sum0 = 0.f, sum1 = 0.f, sum2 = 0.f, sum3 = 0.f;
        #pragma unroll
        for (int t = 0; t < 8; ++t) {
            float h;
            h = acc[t][0]; h = fmaxf(h, 0.2f * h); sum0 = fmaf(h, w2v[t], sum0);
            h = acc[t][1]; h = fmaxf(h, 0.2f * h); sum1 = fmaf(h, w2v[t], sum1);
            h = acc[t][2]; h = fmaxf(h, 0.2f * h); sum2 = fmaf(h, w2v[t], sum2);
            h = acc[t][3]; h = fmaxf(h, 0.2f * h); sum3 = fmaf(h, w2v[t], sum3);
        }
        #pragma unroll
        for (int m = 1; m <= 8; m <<= 1) {
            sum0 += __shfl_xor(sum0, m, 64);
            sum1 += __shfl_xor(sum1, m, 64);
            sum2 += __shfl_xor(sum2, m, 64);
            sum3 += __shfl_xor(sum3, m, 64);
        }
        // softmax over the 16 rows (group g holds rows 4g..4g+3, replicated)
        float mx = fmaxf(fmaxf(sum0, sum1), fmaxf(sum2, sum3));
        mx = fmaxf(mx, __shfl_xor(mx, 16, 64));
        mx = fmaxf(mx, __shfl_xor(mx, 32, 64));
        const float ev0 = __expf(sum0 - mx);
        const float ev1 = __expf(sum1 - mx);
        const float ev2 = __expf(sum2 - mx);
        const float ev3 = __expf(sum3 - mx);
        float es = ev0 + ev1 + ev2 + ev3;
        es += __shfl_xor(es, 16, 64);
        es += __shfl_xor(es, 32, 64);
        const float inv = 1.0f / es;

        // ---- A2 fragment: alpha[k], k = half*8 + j (row-broadcast over l&31)
        bf16x8 a2;
        #pragma unroll
        for (int j = 0; j < 8; ++j) {
            const int src = (((half * 8 + j) >> 2) << 4);   // (k>>2)*16
            float av;
            switch (j & 3) {
                case 0: av = __shfl(ev0, src, 64); break;
                case 1: av = __shfl(ev1, src, 64); break;
                case 2: av = __shfl(ev2, src, 64); break;
                default: av = __shfl(ev3, src, 64); break;
            }
            a2[j] = (__bf16)(av * inv);
        }

        // ---- agg = alpha^T @ nbr via 4x mfma_32x32x16. All C rows are
        // identical (= agg), so EVERY lane's r[0] = agg[t*32 + col]; lanes
        // with half==t>>1 store chunk t -> 2 stores/lane, no idle half-wave.
        f32x16 z;
        #pragma unroll
        for (int i = 0; i < 16; ++i) z[i] = 0.f;

        unsigned short* ao = aggb + (size_t)bn * DDIM;
        #pragma unroll
        for (int t = 0; t < 4; ++t) {
            const f32x16 r = __builtin_amdgcn_mfma_f32_32x32x16_bf16(a2, b2f[t], z, 0, 0, 0);
            if ((t >> 1) == half) {
                const __bf16 rb = (__bf16)r[0];
                ao[t * 32 + col] = __builtin_bit_cast(unsigned short, rb);
            }
        }
    }
}

// ---------------- Kernel 2: out = relu([self | agg] @ w3) -------------------
// MFMA GEMM: 400 blocks x 4 waves, 16 rows/wave, w3 frags staged in LDS.
__global__ __launch_bounds__(256) void k2_out_gemm(
    const float* __restrict__ selfv,          // [BN,128] f32
    const unsigned short* __restrict__ aggb,  // [BN,128] bf16
    const bf16x8* __restrict__ fw3,           // prebuilt fragments
    float* __restrict__ out)                  // [BN,128]
{
    __shared__ bf16x8 w3frag[64][64];  // 64 KB

    const int tid  = threadIdx.x;
    const int lane = tid & 63;
    const int wave = tid >> 6;
    const int grp  = lane >> 4;
    const int lr   = lane & 15;

    #pragma unroll
    for (int c = 0; c < 16; ++c)
        gload_lds16(fw3 + (wave * 16 + c) * 64 + lane, &w3frag[wave * 16 + c][0]);
    __syncthreads();

    const int rowbase = blockIdx.x * 64 + wave * 16;
    const int row = rowbase + lr;

    f32x4 acc[8];
    #pragma unroll
    for (int t = 0; t < 8; ++t) {
        acc[t][0] = 0.f; acc[t][1] = 0.f; acc[t][2] = 0.f; acc[t][3] = 0.f;
    }

    #pragma unroll
    for (int s = 0; s < 8; ++s) {
        bf16x8 af;
        if (s < 4) {
            const int f0 = grp * 8 + 32 * s;
            const float4 x0 = *(const float4*)(selfv + (size_t)row * DDIM + f0);
            const float4 x1 = *(const float4*)(selfv + (size_t)row * DDIM + f0 + 4);
            af[0] = (__bf16)x0.x; af[1] = (__bf16)x0.y;
            af[2] = (__bf16)x0.z; af[3] = (__bf16)x0.w;
            af[4] = (__bf16)x1.x; af[5] = (__bf16)x1.y;
            af[6] = (__bf16)x1.z; af[7] = (__bf16)x1.w;
        } else {
            const int f0 = grp * 8 + 32 * (s - 4);
            af = *(const bf16x8*)(aggb + (size_t)row * DDIM + f0);
        }
        #pragma unroll
        for (int t = 0; t < 8; ++t)
            acc[t] = __builtin_amdgcn_mfma_f32_16x16x32_bf16(af, w3frag[t * 8 + s][lane], acc[t], 0, 0, 0);
    }

    #pragma unroll
    for (int t = 0; t < 8; ++t) {
        #pragma unroll
        for (int j = 0; j < 4; ++j) {
            const int r = rowbase + grp * 4 + j;
            out[(size_t)r * DDIM + t * 16 + lr] = fmaxf(acc[t][j], 0.0f);
        }
    }
}

extern "C" void kernel_launch(void* const* d_in, const int* in_sizes, int n_in,
                              void* d_out, int out_size, void* d_ws, size_t ws_size,
                              hipStream_t stream)
{
    const float* selfv = (const float*)d_in[0];
    const float* nbr   = (const float*)d_in[1];
    const float* wgt   = (const float*)d_in[2];
    const float* extra = (const float*)d_in[3];
    const float* w1    = (const float*)d_in[4];
    const float* w2    = (const float*)d_in[5];
    const float* w3    = (const float*)d_in[6];
    float* out = (float*)d_out;

    // workspace layout: agg bf16 (6.55 MB) | fw1 @ 8 MB (32 KB) | fw3 @ +128 KB (64 KB)
    unsigned short* aggb = (unsigned short*)d_ws;
    bf16x8* fw1 = (bf16x8*)((char*)d_ws + (8u << 20));
    bf16x8* fw3 = (bf16x8*)((char*)d_ws + (8u << 20) + (128u << 10));

    hipLaunchKernelGGL(k0_build_frags, dim3(24), dim3(256), 0, stream, w1, w3, fw1, fw3);
    // 1280 blocks * 4 waves * 5 bn = 25600
    hipLaunchKernelGGL(k1_attn_agg, dim3(1280), dim3(256), 0, stream,
                       nbr, wgt, extra, w1, w2, fw1, aggb);
    hipLaunchKernelGGL(k2_out_gemm, dim3(400), dim3(256), 0, stream,
                       selfv, aggb, fw3, out);
}

// Round 6
// 99.687 us; speedup vs baseline: 1.1431x; 1.1431x over previous
//
#include <hip/hip_runtime.h>
#include <stdint.h>

#define BN_TOTAL 25600   // B*N = 256*100
#define DDIM 128
#define KN 16

typedef __bf16 bf16x8 __attribute__((ext_vector_type(8)));
typedef float f32x4 __attribute__((ext_vector_type(4)));

__device__ __forceinline__ void gload_lds16(const void* g, void* l) {
    __builtin_amdgcn_global_load_lds(
        (const __attribute__((address_space(1))) void*)g,
        (__attribute__((address_space(3))) void*)l, 16, 0, 0);
}

// ---------------- Kernel 0: pre-build w1/w3 bf16 MFMA fragment images --------
// fw1: 32 slots (t*4+s) x 64 lanes of bf16x8 = 32 KB
// fw3: 64 slots (t*8+s) x 64 lanes of bf16x8 = 64 KB
__global__ __launch_bounds__(256) void k0_build_frags(
    const float* __restrict__ w1,   // [129,128]
    const float* __restrict__ w3,   // [256,128]
    bf16x8* __restrict__ fw1,
    bf16x8* __restrict__ fw3)
{
    const int slot = blockIdx.x * 256 + threadIdx.x;   // [0, 6144)
    if (slot < 2048) {
        const int idx  = slot >> 6;        // t*4+s
        const int lane = slot & 63;
        const int t = idx >> 2, s = idx & 3;
        const int grp = lane >> 4, lr = lane & 15;
        const int fbase = grp * 8 + 32 * s;
        const int d = t * 16 + lr;
        bf16x8 tmp;
        #pragma unroll
        for (int j = 0; j < 8; ++j)
            tmp[j] = (__bf16)w1[(fbase + j) * DDIM + d];
        fw1[slot] = tmp;
    } else {
        const int q = slot - 2048;         // [0, 4096)
        const int idx  = q >> 6;           // t*8+s
        const int lane = q & 63;
        const int t = idx >> 3, s = idx & 7;
        const int grp = lane >> 4, lr = lane & 15;
        const int fbase = grp * 8 + 32 * s;
        const int d = t * 16 + lr;
        bf16x8 tmp;
        #pragma unroll
        for (int j = 0; j < 8; ++j)
            tmp[j] = (__bf16)w3[(fbase + j) * DDIM + d];
        fw3[q] = tmp;
    }
}

// ---------------- Kernel 1: logits + softmax -> alpha f32 [BN,16] -----------
// One wave per (b,n). Grid = 6400 blocks x 4 waves. Chain ends at softmax;
// no neighbor re-read, no agg MFMA, no agg store.
__global__ __launch_bounds__(256) void k1_alpha(
    const float* __restrict__ nbr,    // [BN,16,128]
    const float* __restrict__ wgt,    // [BN,16]
    const float* __restrict__ extra,  // [BN,128]
    const float* __restrict__ w1,     // [129,128]
    const float* __restrict__ w2,     // [128]
    const bf16x8* __restrict__ fw1,   // prebuilt fragments
    float* __restrict__ alpha)        // [BN,16] normalized
{
    __shared__ bf16x8 b1frag[32][64];   // 32 KB
    __shared__ float w1last[DDIM];
    __shared__ float w2s[DDIM];

    const int tid  = threadIdx.x;
    const int lane = tid & 63;
    const int wave = tid >> 6;
    const int grp  = lane >> 4;   // 0..3
    const int lr   = lane & 15;   // 0..15

    // stage prebuilt w1 fragments: wave w loads slots w*8 .. w*8+7
    #pragma unroll
    for (int c = 0; c < 8; ++c)
        gload_lds16(fw1 + (wave * 8 + c) * 64 + lane, &b1frag[wave * 8 + c][0]);
    if (tid < DDIM) {
        w1last[tid] = w1[DDIM * DDIM + tid];
        w2s[tid]    = w2[tid];
    }
    __syncthreads();

    const int bn = blockIdx.x * 4 + wave;
    const float* nb = nbr   + (size_t)bn * (KN * DDIM);
    const float* ex = extra + (size_t)bn * DDIM;

    // acc init = weight[r] * w1[128][d]   (rows r = grp*4+j, col d = t*16+lr)
    const float4 wv = *(const float4*)(wgt + (size_t)bn * KN + grp * 4);
    f32x4 acc[8];
    #pragma unroll
    for (int t = 0; t < 8; ++t) {
        const float wl = w1last[t * 16 + lr];
        acc[t][0] = wv.x * wl;
        acc[t][1] = wv.y * wl;
        acc[t][2] = wv.z * wl;
        acc[t][3] = wv.w * wl;
    }

    // ---- stage 1: h = feat @ w1  (A-frags from global, B-frags from LDS)
    #pragma unroll
    for (int s = 0; s < 4; ++s) {
        const int f0 = grp * 8 + 32 * s;
        const float4 n0 = *(const float4*)(nb + lr * DDIM + f0);
        const float4 n1 = *(const float4*)(nb + lr * DDIM + f0 + 4);
        const float4 e0 = *(const float4*)(ex + f0);
        const float4 e1 = *(const float4*)(ex + f0 + 4);
        bf16x8 af;
        af[0] = (__bf16)(n0.x * e0.x); af[1] = (__bf16)(n0.y * e0.y);
        af[2] = (__bf16)(n0.z * e0.z); af[3] = (__bf16)(n0.w * e0.w);
        af[4] = (__bf16)(n1.x * e1.x); af[5] = (__bf16)(n1.y * e1.y);
        af[6] = (__bf16)(n1.z * e1.z); af[7] = (__bf16)(n1.w * e1.w);
        #pragma unroll
        for (int t = 0; t < 8; ++t)
            acc[t] = __builtin_amdgcn_mfma_f32_16x16x32_bf16(
                         af, b1frag[t * 4 + s][lane], acc[t], 0, 0, 0);
    }

    // ---- leaky_relu(0.2) + dot with w2 -> logits for rows grp*4+r
    float sum0 = 0.f, sum1 = 0.f, sum2 = 0.f, sum3 = 0.f;
    #pragma unroll
    for (int t = 0; t < 8; ++t) {
        const float w2v = w2s[t * 16 + lr];
        float h;
        h = acc[t][0]; h = fmaxf(h, 0.2f * h); sum0 = fmaf(h, w2v, sum0);
        h = acc[t][1]; h = fmaxf(h, 0.2f * h); sum1 = fmaf(h, w2v, sum1);
        h = acc[t][2]; h = fmaxf(h, 0.2f * h); sum2 = fmaf(h, w2v, sum2);
        h = acc[t][3]; h = fmaxf(h, 0.2f * h); sum3 = fmaf(h, w2v, sum3);
    }
    #pragma unroll
    for (int m = 1; m <= 8; m <<= 1) {
        sum0 += __shfl_xor(sum0, m, 64);
        sum1 += __shfl_xor(sum1, m, 64);
        sum2 += __shfl_xor(sum2, m, 64);
        sum3 += __shfl_xor(sum3, m, 64);
    }
    // softmax over the 16 rows (group g holds rows 4g..4g+3, replicated)
    float mx = fmaxf(fmaxf(sum0, sum1), fmaxf(sum2, sum3));
    mx = fmaxf(mx, __shfl_xor(mx, 16, 64));
    mx = fmaxf(mx, __shfl_xor(mx, 32, 64));
    const float ev0 = __expf(sum0 - mx);
    const float ev1 = __expf(sum1 - mx);
    const float ev2 = __expf(sum2 - mx);
    const float ev3 = __expf(sum3 - mx);
    float es = ev0 + ev1 + ev2 + ev3;
    es += __shfl_xor(es, 16, 64);
    es += __shfl_xor(es, 32, 64);
    const float inv = 1.0f / es;

    if (lr == 0) {
        float4 av;
        av.x = ev0 * inv; av.y = ev1 * inv; av.z = ev2 * inv; av.w = ev3 * inv;
        *(float4*)(alpha + (size_t)bn * KN + grp * 4) = av;
    }
}

// ---------------- Kernel 2: agg + out = relu([self | agg] @ w3) -------------
// 400 blocks x 4 waves, 16 rows/wave. agg computed in-lane with f32 FMAs
// (lane owns row = lr, f-slice = grp*8 + 32*sp + 0..7); zero cross-lane ops.
// nbr second read is L3-resident (210 MB vs 256 MB L3, just touched by k1).
__global__ __launch_bounds__(256) void k2_fused(
    const float* __restrict__ selfv,  // [BN,128] f32
    const float* __restrict__ nbr,    // [BN,16,128]
    const float* __restrict__ alpha,  // [BN,16] normalized
    const bf16x8* __restrict__ fw3,   // prebuilt fragments
    float* __restrict__ out)          // [BN,128]
{
    __shared__ bf16x8 w3frag[64][64];  // 64 KB -> 2 blocks/CU

    const int tid  = threadIdx.x;
    const int lane = tid & 63;
    const int wave = tid >> 6;
    const int grp  = lane >> 4;
    const int lr   = lane & 15;

    #pragma unroll
    for (int c = 0; c < 16; ++c)
        gload_lds16(fw3 + (wave * 16 + c) * 64 + lane, &w3frag[wave * 16 + c][0]);

    const int rowbase = blockIdx.x * 64 + wave * 16;
    const int row = rowbase + lr;        // = bn for the agg part

    // ---- alpha for this lane's row (normalized; 16 f32)
    const float* ap = alpha + (size_t)row * KN;
    const float4 aA = *(const float4*)(ap);
    const float4 aB = *(const float4*)(ap + 4);
    const float4 aC = *(const float4*)(ap + 8);
    const float4 aD = *(const float4*)(ap + 12);

    // ---- agg[row][grp*8 + 32*sp + j], j=0..7, sp=0..3 (f32 accumulation)
    const float* nbp = nbr + (size_t)row * (KN * DDIM) + grp * 8;
    float ag[4][8];
    #pragma unroll
    for (int sp = 0; sp < 4; ++sp)
        #pragma unroll
        for (int j = 0; j < 8; ++j) ag[sp][j] = 0.f;

#define AGG_K(AV, KBASE)                                                      \
    {                                                                         \
        _Pragma("unroll")                                                     \
        for (int kk = 0; kk < 4; ++kk) {                                      \
            const float ak = (kk == 0) ? (AV).x : (kk == 1) ? (AV).y          \
                             : (kk == 2) ? (AV).z : (AV).w;                   \
            const float* rp = nbp + ((KBASE) + kk) * DDIM;                    \
            _Pragma("unroll")                                                 \
            for (int sp = 0; sp < 4; ++sp) {                                  \
                const float4 x0 = *(const float4*)(rp + sp * 32);             \
                const float4 x1 = *(const float4*)(rp + sp * 32 + 4);         \
                ag[sp][0] = fmaf(ak, x0.x, ag[sp][0]);                        \
                ag[sp][1] = fmaf(ak, x0.y, ag[sp][1]);                        \
                ag[sp][2] = fmaf(ak, x0.z, ag[sp][2]);                        \
                ag[sp][3] = fmaf(ak, x0.w, ag[sp][3]);                        \
                ag[sp][4] = fmaf(ak, x1.x, ag[sp][4]);                        \
                ag[sp][5] = fmaf(ak, x1.y, ag[sp][5]);                        \
                ag[sp][6] = fmaf(ak, x1.z, ag[sp][6]);                        \
                ag[sp][7] = fmaf(ak, x1.w, ag[sp][7]);                        \
            }                                                                 \
        }                                                                     \
    }
    AGG_K(aA, 0)
    AGG_K(aB, 4)
    AGG_K(aC, 8)
    AGG_K(aD, 12)
#undef AGG_K

    // convert agg slices to bf16 A-fragments for s = 4..7
    bf16x8 afA[4];
    #pragma unroll
    for (int sp = 0; sp < 4; ++sp)
        #pragma unroll
        for (int j = 0; j < 8; ++j)
            afA[sp][j] = (__bf16)ag[sp][j];

    __syncthreads();   // w3frag staged (gload_lds drained by barrier)

    f32x4 acc[8];
    #pragma unroll
    for (int t = 0; t < 8; ++t) {
        acc[t][0] = 0.f; acc[t][1] = 0.f; acc[t][2] = 0.f; acc[t][3] = 0.f;
    }

    // self half: s = 0..3
    #pragma unroll
    for (int s = 0; s < 4; ++s) {
        const int f0 = grp * 8 + 32 * s;
        const float4 x0 = *(const float4*)(selfv + (size_t)row * DDIM + f0);
        const float4 x1 = *(const float4*)(selfv + (size_t)row * DDIM + f0 + 4);
        bf16x8 af;
        af[0] = (__bf16)x0.x; af[1] = (__bf16)x0.y;
        af[2] = (__bf16)x0.z; af[3] = (__bf16)x0.w;
        af[4] = (__bf16)x1.x; af[5] = (__bf16)x1.y;
        af[6] = (__bf16)x1.z; af[7] = (__bf16)x1.w;
        #pragma unroll
        for (int t = 0; t < 8; ++t)
            acc[t] = __builtin_amdgcn_mfma_f32_16x16x32_bf16(
                         af, w3frag[t * 8 + s][lane], acc[t], 0, 0, 0);
    }
    // agg half: s = 4..7
    #pragma unroll
    for (int sp = 0; sp < 4; ++sp) {
        #pragma unroll
        for (int t = 0; t < 8; ++t)
            acc[t] = __builtin_amdgcn_mfma_f32_16x16x32_bf16(
                         afA[sp], w3frag[t * 8 + 4 + sp][lane], acc[t], 0, 0, 0);
    }

    #pragma unroll
    for (int t = 0; t < 8; ++t) {
        #pragma unroll
        for (int j = 0; j < 4; ++j) {
            const int r = rowbase + grp * 4 + j;
            out[(size_t)r * DDIM + t * 16 + lr] = fmaxf(acc[t][j], 0.0f);
        }
    }
}

extern "C" void kernel_launch(void* const* d_in, const int* in_sizes, int n_in,
                              void* d_out, int out_size, void* d_ws, size_t ws_size,
                              hipStream_t stream)
{
    const float* selfv = (const float*)d_in[0];
    const float* nbr   = (const float*)d_in[1];
    const float* wgt   = (const float*)d_in[2];
    const float* extra = (const float*)d_in[3];
    const float* w1    = (const float*)d_in[4];
    const float* w2    = (const float*)d_in[5];
    const float* w3    = (const float*)d_in[6];
    float* out = (float*)d_out;

    // workspace: alpha f32 [BN,16] (1.64 MB) | fw1 @ 8 MB (32 KB) | fw3 @ +128 KB (64 KB)
    float* alpha = (float*)d_ws;
    bf16x8* fw1 = (bf16x8*)((char*)d_ws + (8u << 20));
    bf16x8* fw3 = (bf16x8*)((char*)d_ws + (8u << 20) + (128u << 10));

    hipLaunchKernelGGL(k0_build_frags, dim3(24), dim3(256), 0, stream, w1, w3, fw1, fw3);
    hipLaunchKernelGGL(k1_alpha, dim3(6400), dim3(256), 0, stream,
                       nbr, wgt, extra, w1, w2, fw1, alpha);
    hipLaunchKernelGGL(k2_fused, dim3(400), dim3(256), 0, stream,
                       selfv, nbr, alpha, fw3, out);
}

// Round 7
// 75.738 us; speedup vs baseline: 1.5046x; 1.3162x over previous
//
#include <hip/hip_runtime.h>
#include <stdint.h>

#define BN_TOTAL 25600   // B*N = 256*100
#define DDIM 128
#define KN 16

typedef __bf16 bf16x8 __attribute__((ext_vector_type(8)));
typedef float f32x4 __attribute__((ext_vector_type(4)));
typedef float f32x16 __attribute__((ext_vector_type(16)));

__device__ __forceinline__ void gload_lds16(const void* g, void* l) {
    __builtin_amdgcn_global_load_lds(
        (const __attribute__((address_space(1))) void*)g,
        (__attribute__((address_space(3))) void*)l, 16, 0, 0);
}

// ---------------- Kernel 0: pre-build w1/w3 bf16 MFMA fragment images --------
// fw1: 32 slots (t*4+s) x 64 lanes of bf16x8 = 32 KB
// fw3: 64 slots (t*8+s) x 64 lanes of bf16x8 = 64 KB
__global__ __launch_bounds__(256) void k0_build_frags(
    const float* __restrict__ w1,   // [129,128]
    const float* __restrict__ w3,   // [256,128]
    bf16x8* __restrict__ fw1,
    bf16x8* __restrict__ fw3)
{
    const int slot = blockIdx.x * 256 + threadIdx.x;   // [0, 6144)
    if (slot < 2048) {
        const int idx  = slot >> 6;        // t*4+s
        const int lane = slot & 63;
        const int t = idx >> 2, s = idx & 3;
        const int grp = lane >> 4, lr = lane & 15;
        const int fbase = grp * 8 + 32 * s;
        const int d = t * 16 + lr;
        bf16x8 tmp;
        #pragma unroll
        for (int j = 0; j < 8; ++j)
            tmp[j] = (__bf16)w1[(fbase + j) * DDIM + d];
        fw1[slot] = tmp;
    } else {
        const int q = slot - 2048;         // [0, 4096)
        const int idx  = q >> 6;           // t*8+s
        const int lane = q & 63;
        const int t = idx >> 3, s = idx & 7;
        const int grp = lane >> 4, lr = lane & 15;
        const int fbase = grp * 8 + 32 * s;
        const int d = t * 16 + lr;
        bf16x8 tmp;
        #pragma unroll
        for (int j = 0; j < 8; ++j)
            tmp[j] = (__bf16)w3[(fbase + j) * DDIM + d];
        fw3[q] = tmp;
    }
}

// ---------------- Kernel 1: attention + aggregation -> agg bf16 [BN][128] ----
// One wave per (b,n). Grid = 6400 blocks x 4 waves. LDS = exactly 32 KB
// (b1frag only) -> 5 blocks/CU. w1last/w2 slices live in registers.
__global__ __launch_bounds__(256) void k1_attn_agg(
    const float* __restrict__ nbr,    // [BN,16,128]
    const float* __restrict__ wgt,    // [BN,16]
    const float* __restrict__ extra,  // [BN,128]
    const float* __restrict__ w1,     // [129,128]
    const float* __restrict__ w2,     // [128]
    const bf16x8* __restrict__ fw1,   // prebuilt fragments
    unsigned short* __restrict__ aggb)// [BN,128] bf16
{
    __shared__ bf16x8 b1frag[32][64];   // exactly 32768 B

    const int tid  = threadIdx.x;
    const int lane = tid & 63;
    const int wave = tid >> 6;
    const int grp  = lane >> 4;   // 0..3
    const int lr   = lane & 15;   // 0..15
    const int half = lane >> 5;   // 0..1  (32x32 MFMA)
    const int col  = lane & 31;   // 0..31 (32x32 MFMA)

    const int bn = blockIdx.x * 4 + wave;
    const float* nb = nbr   + (size_t)bn * (KN * DDIM);
    const float* ex = extra + (size_t)bn * DDIM;

    // ---- per-lane weight columns from global (L2-broadcast), replaces LDS
    float wl[8], w2v[8];
    #pragma unroll
    for (int t = 0; t < 8; ++t) {
        wl[t]  = w1[DDIM * DDIM + t * 16 + lr];   // row 128 of w1
        w2v[t] = w2[t * 16 + lr];
    }

    // ---- prefetch (issued before the staging barrier): wgt + s=0 A-tile
    const float4 wv   = *(const float4*)(wgt + (size_t)bn * KN + grp * 4);
    const float4 p_n0 = *(const float4*)(nb + lr * DDIM + grp * 8);
    const float4 p_n1 = *(const float4*)(nb + lr * DDIM + grp * 8 + 4);
    const float4 p_e0 = *(const float4*)(ex + grp * 8);
    const float4 p_e1 = *(const float4*)(ex + grp * 8 + 4);

    // stage prebuilt w1 fragments: wave w loads slots w*8 .. w*8+7
    #pragma unroll
    for (int c = 0; c < 8; ++c)
        gload_lds16(fw1 + (wave * 8 + c) * 64 + lane, &b1frag[wave * 8 + c][0]);
    __syncthreads();

    // acc init = weight[r] * w1[128][d]   (rows r = grp*4+j, col d = t*16+lr)
    f32x4 acc[8];
    #pragma unroll
    for (int t = 0; t < 8; ++t) {
        acc[t][0] = wv.x * wl[t];
        acc[t][1] = wv.y * wl[t];
        acc[t][2] = wv.z * wl[t];
        acc[t][3] = wv.w * wl[t];
    }

    // ---- stage 1: h = feat @ w1  (A-frags from global, B-frags from LDS)
    #pragma unroll
    for (int s = 0; s < 4; ++s) {
        const int f0 = grp * 8 + 32 * s;
        float4 n0, n1, e0, e1;
        if (s == 0) { n0 = p_n0; n1 = p_n1; e0 = p_e0; e1 = p_e1; }
        else {
            n0 = *(const float4*)(nb + lr * DDIM + f0);
            n1 = *(const float4*)(nb + lr * DDIM + f0 + 4);
            e0 = *(const float4*)(ex + f0);
            e1 = *(const float4*)(ex + f0 + 4);
        }
        bf16x8 af;
        af[0] = (__bf16)(n0.x * e0.x); af[1] = (__bf16)(n0.y * e0.y);
        af[2] = (__bf16)(n0.z * e0.z); af[3] = (__bf16)(n0.w * e0.w);
        af[4] = (__bf16)(n1.x * e1.x); af[5] = (__bf16)(n1.y * e1.y);
        af[6] = (__bf16)(n1.z * e1.z); af[7] = (__bf16)(n1.w * e1.w);
        #pragma unroll
        for (int t = 0; t < 8; ++t)
            acc[t] = __builtin_amdgcn_mfma_f32_16x16x32_bf16(
                         af, b1frag[t * 4 + s][lane], acc[t], 0, 0, 0);
    }

    // ---- issue stage-2 B loads now (tile L1-hot); consumed after softmax,
    // latency hides under the shuffle/exp chain.
    // lane needs nbr[k = half*8+j][f = t*32+col]
    bf16x8 b2f[4];
    #pragma unroll
    for (int t = 0; t < 4; ++t)
        #pragma unroll
        for (int j = 0; j < 8; ++j)
            b2f[t][j] = (__bf16)nb[(half * 8 + j) * DDIM + t * 32 + col];

    // ---- leaky_relu(0.2) + dot with w2 -> logits for rows grp*4+r
    float sum0 = 0.f, sum1 = 0.f, sum2 = 0.f, sum3 = 0.f;
    #pragma unroll
    for (int t = 0; t < 8; ++t) {
        float h;
        h = acc[t][0]; h = fmaxf(h, 0.2f * h); sum0 = fmaf(h, w2v[t], sum0);
        h = acc[t][1]; h = fmaxf(h, 0.2f * h); sum1 = fmaf(h, w2v[t], sum1);
        h = acc[t][2]; h = fmaxf(h, 0.2f * h); sum2 = fmaf(h, w2v[t], sum2);
        h = acc[t][3]; h = fmaxf(h, 0.2f * h); sum3 = fmaf(h, w2v[t], sum3);
    }
    #pragma unroll
    for (int m = 1; m <= 8; m <<= 1) {
        sum0 += __shfl_xor(sum0, m, 64);
        sum1 += __shfl_xor(sum1, m, 64);
        sum2 += __shfl_xor(sum2, m, 64);
        sum3 += __shfl_xor(sum3, m, 64);
    }
    // softmax over the 16 rows (group g holds rows 4g..4g+3, replicated)
    float mx = fmaxf(fmaxf(sum0, sum1), fmaxf(sum2, sum3));
    mx = fmaxf(mx, __shfl_xor(mx, 16, 64));
    mx = fmaxf(mx, __shfl_xor(mx, 32, 64));
    const float ev0 = __expf(sum0 - mx);
    const float ev1 = __expf(sum1 - mx);
    const float ev2 = __expf(sum2 - mx);
    const float ev3 = __expf(sum3 - mx);
    float es = ev0 + ev1 + ev2 + ev3;
    es += __shfl_xor(es, 16, 64);
    es += __shfl_xor(es, 32, 64);
    const float inv = 1.0f / es;

    // ---- A2 fragment: alpha[k], k = half*8 + j (row-broadcast over l&31)
    bf16x8 a2;
    #pragma unroll
    for (int j = 0; j < 8; ++j) {
        const int src = (((half * 8 + j) >> 2) << 4);   // (k>>2)*16
        float av;
        switch (j & 3) {
            case 0: av = __shfl(ev0, src, 64); break;
            case 1: av = __shfl(ev1, src, 64); break;
            case 2: av = __shfl(ev2, src, 64); break;
            default: av = __shfl(ev3, src, 64); break;
        }
        a2[j] = (__bf16)(av * inv);
    }

    // ---- agg = alpha^T @ nbr via 4x mfma_32x32x16. All C rows identical
    // (= agg), so every lane's r[0] = agg[t*32+col]; half-waves split tiles.
    f32x16 z;
    #pragma unroll
    for (int i = 0; i < 16; ++i) z[i] = 0.f;

    unsigned short* ao = aggb + (size_t)bn * DDIM;
    #pragma unroll
    for (int t = 0; t < 4; ++t) {
        const f32x16 r = __builtin_amdgcn_mfma_f32_32x32x16_bf16(a2, b2f[t], z, 0, 0, 0);
        if ((t >> 1) == half) {
            const __bf16 rb = (__bf16)r[0];
            ao[t * 32 + col] = __builtin_bit_cast(unsigned short, rb);
        }
    }
}

// ---------------- Kernel 2: out = relu([self | agg] @ w3) -------------------
// MFMA GEMM: 400 blocks x 4 waves, 16 rows/wave, w3 frags staged in LDS.
__global__ __launch_bounds__(256) void k2_out_gemm(
    const float* __restrict__ selfv,          // [BN,128] f32
    const unsigned short* __restrict__ aggb,  // [BN,128] bf16
    const bf16x8* __restrict__ fw3,           // prebuilt fragments
    float* __restrict__ out)                  // [BN,128]
{
    __shared__ bf16x8 w3frag[64][64];  // 64 KB

    const int tid  = threadIdx.x;
    const int lane = tid & 63;
    const int wave = tid >> 6;
    const int grp  = lane >> 4;
    const int lr   = lane & 15;

    #pragma unroll
    for (int c = 0; c < 16; ++c)
        gload_lds16(fw3 + (wave * 16 + c) * 64 + lane, &w3frag[wave * 16 + c][0]);
    __syncthreads();

    const int rowbase = blockIdx.x * 64 + wave * 16;
    const int row = rowbase + lr;

    f32x4 acc[8];
    #pragma unroll
    for (int t = 0; t < 8; ++t) {
        acc[t][0] = 0.f; acc[t][1] = 0.f; acc[t][2] = 0.f; acc[t][3] = 0.f;
    }

    #pragma unroll
    for (int s = 0; s < 8; ++s) {
        bf16x8 af;
        if (s < 4) {
            const int f0 = grp * 8 + 32 * s;
            const float4 x0 = *(const float4*)(selfv + (size_t)row * DDIM + f0);
            const float4 x1 = *(const float4*)(selfv + (size_t)row * DDIM + f0 + 4);
            af[0] = (__bf16)x0.x; af[1] = (__bf16)x0.y;
            af[2] = (__bf16)x0.z; af[3] = (__bf16)x0.w;
            af[4] = (__bf16)x1.x; af[5] = (__bf16)x1.y;
            af[6] = (__bf16)x1.z; af[7] = (__bf16)x1.w;
        } else {
            const int f0 = grp * 8 + 32 * (s - 4);
            af = *(const bf16x8*)(aggb + (size_t)row * DDIM + f0);
        }
        #pragma unroll
        for (int t = 0; t < 8; ++t)
            acc[t] = __builtin_amdgcn_mfma_f32_16x16x32_bf16(
                         af, w3frag[t * 8 + s][lane], acc[t], 0, 0, 0);
    }

    #pragma unroll
    for (int t = 0; t < 8; ++t) {
        #pragma unroll
        for (int j = 0; j < 4; ++j) {
            const int r = rowbase + grp * 4 + j;
            out[(size_t)r * DDIM + t * 16 + lr] = fmaxf(acc[t][j], 0.0f);
        }
    }
}

extern "C" void kernel_launch(void* const* d_in, const int* in_sizes, int n_in,
                              void* d_out, int out_size, void* d_ws, size_t ws_size,
                              hipStream_t stream)
{
    const float* selfv = (const float*)d_in[0];
    const float* nbr   = (const float*)d_in[1];
    const float* wgt   = (const float*)d_in[2];
    const float* extra = (const float*)d_in[3];
    const float* w1    = (const float*)d_in[4];
    const float* w2    = (const float*)d_in[5];
    const float* w3    = (const float*)d_in[6];
    float* out = (float*)d_out;

    // workspace layout: agg bf16 (6.55 MB) | fw1 @ 8 MB (32 KB) | fw3 @ +128 KB (64 KB)
    unsigned short* aggb = (unsigned short*)d_ws;
    bf16x8* fw1 = (bf16x8*)((char*)d_ws + (8u << 20));
    bf16x8* fw3 = (bf16x8*)((char*)d_ws + (8u << 20) + (128u << 10));

    hipLaunchKernelGGL(k0_build_frags, dim3(24), dim3(256), 0, stream, w1, w3, fw1, fw3);
    hipLaunchKernelGGL(k1_attn_agg, dim3(6400), dim3(256), 0, stream,
                       nbr, wgt, extra, w1, w2, fw1, aggb);
    hipLaunchKernelGGL(k2_out_gemm, dim3(400), dim3(256), 0, stream,
                       selfv, aggb, fw3, out);
}

// Round 8
// 71.803 us; speedup vs baseline: 1.5871x; 1.0548x over previous
//
#include <hip/hip_runtime.h>
#include <stdint.h>

#define BN_TOTAL 25600   // B*N = 256*100
#define DDIM 128
#define KN 16

typedef __bf16 bf16x8 __attribute__((ext_vector_type(8)));
typedef float f32x4 __attribute__((ext_vector_type(4)));
typedef float f32x16 __attribute__((ext_vector_type(16)));

__device__ __forceinline__ void gload_lds16(const void* g, void* l) {
    __builtin_amdgcn_global_load_lds(
        (const __attribute__((address_space(1))) void*)g,
        (__attribute__((address_space(3))) void*)l, 16, 0, 0);
}

// ---------------- Kernel 0: pre-build w1/w3 bf16 MFMA fragment images --------
// fw1: 32 slots (t*4+s) x 64 lanes of bf16x8 = 32 KB
// fw3: 64 slots (t*8+s) x 64 lanes of bf16x8 = 64 KB
__global__ __launch_bounds__(256) void k0_build_frags(
    const float* __restrict__ w1,   // [129,128]
    const float* __restrict__ w3,   // [256,128]
    bf16x8* __restrict__ fw1,
    bf16x8* __restrict__ fw3)
{
    const int slot = blockIdx.x * 256 + threadIdx.x;   // [0, 6144)
    if (slot < 2048) {
        const int idx  = slot >> 6;        // t*4+s
        const int lane = slot & 63;
        const int t = idx >> 2, s = idx & 3;
        const int grp = lane >> 4, lr = lane & 15;
        const int fbase = grp * 8 + 32 * s;
        const int d = t * 16 + lr;
        bf16x8 tmp;
        #pragma unroll
        for (int j = 0; j < 8; ++j)
            tmp[j] = (__bf16)w1[(fbase + j) * DDIM + d];
        fw1[slot] = tmp;
    } else {
        const int q = slot - 2048;         // [0, 4096)
        const int idx  = q >> 6;           // t*8+s
        const int lane = q & 63;
        const int t = idx >> 3, s = idx & 7;
        const int grp = lane >> 4, lr = lane & 15;
        const int fbase = grp * 8 + 32 * s;
        const int d = t * 16 + lr;
        bf16x8 tmp;
        #pragma unroll
        for (int j = 0; j < 8; ++j)
            tmp[j] = (__bf16)w3[(fbase + j) * DDIM + d];
        fw3[q] = tmp;
    }
}

// ---------------- Kernel 1: attention + aggregation -> agg bf16 [BN][128] ----
// One wave per (b,n). 3200 blocks x 8 waves (512 thr). launch_bounds(512,6)
// caps VGPR at ~85 -> up to 24 waves/CU; 8 waves share one staging barrier.
__global__ __launch_bounds__(512, 6) void k1_attn_agg(
    const float* __restrict__ nbr,    // [BN,16,128]
    const float* __restrict__ wgt,    // [BN,16]
    const float* __restrict__ extra,  // [BN,128]
    const float* __restrict__ w1,     // [129,128]
    const float* __restrict__ w2,     // [128]
    const bf16x8* __restrict__ fw1,   // prebuilt fragments
    unsigned short* __restrict__ aggb)// [BN,128] bf16
{
    __shared__ bf16x8 b1frag[32][64];   // 32 KB
    __shared__ float w1last[DDIM];
    __shared__ float w2s[DDIM];

    const int tid  = threadIdx.x;
    const int lane = tid & 63;
    const int wave = tid >> 6;    // 0..7
    const int grp  = lane >> 4;   // 0..3
    const int lr   = lane & 15;   // 0..15
    const int half = lane >> 5;   // 0..1  (32x32 MFMA)
    const int col  = lane & 31;   // 0..31 (32x32 MFMA)

    // stage prebuilt w1 fragments: wave w loads slots w*4 .. w*4+3
    #pragma unroll
    for (int c = 0; c < 4; ++c)
        gload_lds16(fw1 + (wave * 4 + c) * 64 + lane, &b1frag[wave * 4 + c][0]);
    if (tid < DDIM)            w1last[tid] = w1[DDIM * DDIM + tid];
    else if (tid < 2 * DDIM)   w2s[tid - DDIM] = w2[tid - DDIM];
    __syncthreads();

    const int bn = blockIdx.x * 8 + wave;
    const float* nb = nbr   + (size_t)bn * (KN * DDIM);
    const float* ex = extra + (size_t)bn * DDIM;

    // acc init = weight[r] * w1[128][d]   (rows r = grp*4+j, col d = t*16+lr)
    const float4 wv = *(const float4*)(wgt + (size_t)bn * KN + grp * 4);
    f32x4 acc[8];
    #pragma unroll
    for (int t = 0; t < 8; ++t) {
        const float wl = w1last[t * 16 + lr];
        acc[t][0] = wv.x * wl;
        acc[t][1] = wv.y * wl;
        acc[t][2] = wv.z * wl;
        acc[t][3] = wv.w * wl;
    }

    // ---- stage 1: h = feat @ w1  (A-frags from global, B-frags from LDS)
    #pragma unroll
    for (int s = 0; s < 4; ++s) {
        const int f0 = grp * 8 + 32 * s;
        const float4 n0 = *(const float4*)(nb + lr * DDIM + f0);
        const float4 n1 = *(const float4*)(nb + lr * DDIM + f0 + 4);
        const float4 e0 = *(const float4*)(ex + f0);
        const float4 e1 = *(const float4*)(ex + f0 + 4);
        bf16x8 af;
        af[0] = (__bf16)(n0.x * e0.x); af[1] = (__bf16)(n0.y * e0.y);
        af[2] = (__bf16)(n0.z * e0.z); af[3] = (__bf16)(n0.w * e0.w);
        af[4] = (__bf16)(n1.x * e1.x); af[5] = (__bf16)(n1.y * e1.y);
        af[6] = (__bf16)(n1.z * e1.z); af[7] = (__bf16)(n1.w * e1.w);
        #pragma unroll
        for (int t = 0; t < 8; ++t)
            acc[t] = __builtin_amdgcn_mfma_f32_16x16x32_bf16(
                         af, b1frag[t * 4 + s][lane], acc[t], 0, 0, 0);
    }

    // ---- issue stage-2 B loads now (tile L1-hot); consumed after softmax,
    // latency hides under the shuffle/exp chain.
    // lane needs nbr[k = half*8+j][f = t*32+col]
    bf16x8 b2f[4];
    #pragma unroll
    for (int t = 0; t < 4; ++t)
        #pragma unroll
        for (int j = 0; j < 8; ++j)
            b2f[t][j] = (__bf16)nb[(half * 8 + j) * DDIM + t * 32 + col];

    // ---- leaky_relu(0.2) + dot with w2 -> logits for rows grp*4+r
    float sum0 = 0.f, sum1 = 0.f, sum2 = 0.f, sum3 = 0.f;
    #pragma unroll
    for (int t = 0; t < 8; ++t) {
        const float w2v = w2s[t * 16 + lr];
        float h;
        h = acc[t][0]; h = fmaxf(h, 0.2f * h); sum0 = fmaf(h, w2v, sum0);
        h = acc[t][1]; h = fmaxf(h, 0.2f * h); sum1 = fmaf(h, w2v, sum1);
        h = acc[t][2]; h = fmaxf(h, 0.2f * h); sum2 = fmaf(h, w2v, sum2);
        h = acc[t][3]; h = fmaxf(h, 0.2f * h); sum3 = fmaf(h, w2v, sum3);
    }
    #pragma unroll
    for (int m = 1; m <= 8; m <<= 1) {
        sum0 += __shfl_xor(sum0, m, 64);
        sum1 += __shfl_xor(sum1, m, 64);
        sum2 += __shfl_xor(sum2, m, 64);
        sum3 += __shfl_xor(sum3, m, 64);
    }
    // softmax over the 16 rows (group g holds rows 4g..4g+3, replicated)
    float mx = fmaxf(fmaxf(sum0, sum1), fmaxf(sum2, sum3));
    mx = fmaxf(mx, __shfl_xor(mx, 16, 64));
    mx = fmaxf(mx, __shfl_xor(mx, 32, 64));
    const float ev0 = __expf(sum0 - mx);
    const float ev1 = __expf(sum1 - mx);
    const float ev2 = __expf(sum2 - mx);
    const float ev3 = __expf(sum3 - mx);
    float es = ev0 + ev1 + ev2 + ev3;
    es += __shfl_xor(es, 16, 64);
    es += __shfl_xor(es, 32, 64);
    const float inv = 1.0f / es;

    // ---- A2 fragment: alpha[k], k = half*8 + j (row-broadcast over l&31)
    bf16x8 a2;
    #pragma unroll
    for (int j = 0; j < 8; ++j) {
        const int src = (((half * 8 + j) >> 2) << 4);   // (k>>2)*16
        float av;
        switch (j & 3) {
            case 0: av = __shfl(ev0, src, 64); break;
            case 1: av = __shfl(ev1, src, 64); break;
            case 2: av = __shfl(ev2, src, 64); break;
            default: av = __shfl(ev3, src, 64); break;
        }
        a2[j] = (__bf16)(av * inv);
    }

    // ---- agg = alpha^T @ nbr via 4x mfma_32x32x16. All C rows identical
    // (= agg), so every lane's r[0] = agg[t*32+col]; half-waves split tiles.
    f32x16 z;
    #pragma unroll
    for (int i = 0; i < 16; ++i) z[i] = 0.f;

    unsigned short* ao = aggb + (size_t)bn * DDIM;
    #pragma unroll
    for (int t = 0; t < 4; ++t) {
        const f32x16 r = __builtin_amdgcn_mfma_f32_32x32x16_bf16(a2, b2f[t], z, 0, 0, 0);
        if ((t >> 1) == half) {
            const __bf16 rb = (__bf16)r[0];
            ao[t * 32 + col] = __builtin_bit_cast(unsigned short, rb);
        }
    }
}

// ---------------- Kernel 2: out = relu([self | agg] @ w3) -------------------
// 200 blocks x 8 waves (512 thr), 128 rows/block — single generation.
__global__ __launch_bounds__(512, 4) void k2_out_gemm(
    const float* __restrict__ selfv,          // [BN,128] f32
    const unsigned short* __restrict__ aggb,  // [BN,128] bf16
    const bf16x8* __restrict__ fw3,           // prebuilt fragments
    float* __restrict__ out)                  // [BN,128]
{
    __shared__ bf16x8 w3frag[64][64];  // 64 KB

    const int tid  = threadIdx.x;
    const int lane = tid & 63;
    const int wave = tid >> 6;    // 0..7
    const int grp  = lane >> 4;
    const int lr   = lane & 15;

    #pragma unroll
    for (int c = 0; c < 8; ++c)
        gload_lds16(fw3 + (wave * 8 + c) * 64 + lane, &w3frag[wave * 8 + c][0]);
    __syncthreads();

    const int rowbase = blockIdx.x * 128 + wave * 16;
    const int row = rowbase + lr;

    f32x4 acc[8];
    #pragma unroll
    for (int t = 0; t < 8; ++t) {
        acc[t][0] = 0.f; acc[t][1] = 0.f; acc[t][2] = 0.f; acc[t][3] = 0.f;
    }

    #pragma unroll
    for (int s = 0; s < 8; ++s) {
        bf16x8 af;
        if (s < 4) {
            const int f0 = grp * 8 + 32 * s;
            const float4 x0 = *(const float4*)(selfv + (size_t)row * DDIM + f0);
            const float4 x1 = *(const float4*)(selfv + (size_t)row * DDIM + f0 + 4);
            af[0] = (__bf16)x0.x; af[1] = (__bf16)x0.y;
            af[2] = (__bf16)x0.z; af[3] = (__bf16)x0.w;
            af[4] = (__bf16)x1.x; af[5] = (__bf16)x1.y;
            af[6] = (__bf16)x1.z; af[7] = (__bf16)x1.w;
        } else {
            const int f0 = grp * 8 + 32 * (s - 4);
            af = *(const bf16x8*)(aggb + (size_t)row * DDIM + f0);
        }
        #pragma unroll
        for (int t = 0; t < 8; ++t)
            acc[t] = __builtin_amdgcn_mfma_f32_16x16x32_bf16(
                         af, w3frag[t * 8 + s][lane], acc[t], 0, 0, 0);
    }

    #pragma unroll
    for (int t = 0; t < 8; ++t) {
        #pragma unroll
        for (int j = 0; j < 4; ++j) {
            const int r = rowbase + grp * 4 + j;
            out[(size_t)r * DDIM + t * 16 + lr] = fmaxf(acc[t][j], 0.0f);
        }
    }
}

extern "C" void kernel_launch(void* const* d_in, const int* in_sizes, int n_in,
                              void* d_out, int out_size, void* d_ws, size_t ws_size,
                              hipStream_t stream)
{
    const float* selfv = (const float*)d_in[0];
    const float* nbr   = (const float*)d_in[1];
    const float* wgt   = (const float*)d_in[2];
    const float* extra = (const float*)d_in[3];
    const float* w1    = (const float*)d_in[4];
    const float* w2    = (const float*)d_in[5];
    const float* w3    = (const float*)d_in[6];
    float* out = (float*)d_out;

    // workspace layout: agg bf16 (6.55 MB) | fw1 @ 8 MB (32 KB) | fw3 @ +128 KB (64 KB)
    unsigned short* aggb = (unsigned short*)d_ws;
    bf16x8* fw1 = (bf16x8*)((char*)d_ws + (8u << 20));
    bf16x8* fw3 = (bf16x8*)((char*)d_ws + (8u << 20) + (128u << 10));

    hipLaunchKernelGGL(k0_build_frags, dim3(24), dim3(256), 0, stream, w1, w3, fw1, fw3);
    // 3200 blocks * 8 waves = 25600 bn
    hipLaunchKernelGGL(k1_attn_agg, dim3(3200), dim3(512), 0, stream,
                       nbr, wgt, extra, w1, w2, fw1, aggb);
    // 200 blocks * 128 rows = 25600 rows
    hipLaunchKernelGGL(k2_out_gemm, dim3(200), dim3(512), 0, stream,
                       selfv, aggb, fw3, out);
}